// Round 2
// baseline (294429.810 us; speedup 1.0000x reference)
//
#include <hip/hip_runtime.h>
#include <cstddef>

typedef float f32x2 __attribute__((ext_vector_type(2)));

__device__ __forceinline__ float fast_tanh(float x) {
    // tanh(x) = (e^{2x}-1)/(e^{2x}+1); clamp to avoid inf/inf
    x = fminf(15.f, fmaxf(-15.f, x));
    float e = __expf(2.f * x);
    return (e - 1.f) * __builtin_amdgcn_rcpf(e + 1.f);
}

// launch_bounds(256,1): VGPR cap 512. With (256,2) the 256-reg cap forced the
// compiler to spill c1/h1v/dv (192 floats) to scratch -> 357 GB HBM traffic,
// VALUBusy 1.6%. Registers must hold the per-sample state.
__global__ __launch_bounds__(256, 1)
void cnf_rk4_kernel(const float* __restrict__ x,
                    const float* __restrict__ ctx,
                    const float* __restrict__ eps,
                    const float* __restrict__ W1,
                    const float* __restrict__ b1,
                    const float* __restrict__ W2,
                    const float* __restrict__ b2,
                    const float* __restrict__ W3,
                    const float* __restrict__ b3,
                    float* __restrict__ out,
                    int nb)
{
    // W1 is [67][64]: rows 0,1 = z part, rows 2..65 = context part, row 66 = t.
    __shared__ __align__(16) float sW1z[2 * 64];
    __shared__ __align__(16) float sW1c[64 * 64];
    __shared__ __align__(16) float sW1t[64];
    __shared__ __align__(16) float sW2[64 * 64];    // [i][j] row-major (bwd: row i contiguous)
    __shared__ __align__(16) float sW2T[64 * 64];   // [j][i] (fwd: row j contiguous)
    __shared__ __align__(16) float sW3[128];        // [j][2]
    __shared__ __align__(16) float sb1[64];
    __shared__ __align__(16) float sb2[64];
    __shared__ float sb3[2];

    const int tid = threadIdx.x;
    for (int idx = tid; idx < 64 * 64; idx += 256) {
        sW1c[idx] = W1[(2 + (idx >> 6)) * 64 + (idx & 63)];
        float v = W2[idx];
        sW2[idx] = v;
        sW2T[(idx & 63) * 64 + (idx >> 6)] = v;
    }
    if (tid < 128) { sW1z[tid] = W1[tid]; sW3[tid] = W3[tid]; }
    if (tid >= 128 && tid < 192) sW1t[tid - 128] = W1[66 * 64 + (tid - 128)];
    if (tid >= 192) sb1[tid - 192] = b1[tid - 192];
    if (tid < 64) sb2[tid] = b2[tid];
    if (tid == 0) { sb3[0] = b3[0]; sb3[1] = b3[1]; }
    __syncthreads();

    const int s = blockIdx.x * 256 + tid;
    if (s >= nb) return;

    // c1 = b1 + ctx @ W1[2:66]  (context contribution is constant across all stages)
    float c1[64];
    #pragma unroll
    for (int j = 0; j < 64; ++j) c1[j] = sb1[j];
    const float* cp = ctx + (size_t)s * 64;
    #pragma unroll 1
    for (int m = 0; m < 64; ++m) {
        float cm = cp[m];
        const float* wr = sW1c + m * 64;
        #pragma unroll
        for (int j = 0; j < 64; ++j) c1[j] = __fmaf_rn(cm, wr[j], c1[j]);
    }

    float z0 = x[2 * s], z1 = x[2 * s + 1];
    float lp = 0.f;
    const float hstep = -1.f / 9.f;

    float h1v[64];
    float dv[64];

    #pragma unroll 1
    for (int k = 0; k < 9; ++k) {
        float ti = 1.f + (float)k * hstep;
        float ze0 = z0, ze1 = z1;
        float zs0 = 0.f, zs1 = 0.f, ls = 0.f;
        #pragma unroll 1
        for (int st = 0; st < 4; ++st) {
            float coef = (st == 0) ? 0.f : ((st == 3) ? 1.f : 0.5f);
            float tcur = ti + coef * hstep;
            const float* ep = eps + ((size_t)(k * 4 + st) * (size_t)nb + (size_t)s) * 2;
            float e0 = ep[0], e1 = ep[1];

            // layer 1: pre = c1 + ze0*W1[0] + ze1*W1[1] + t*W1[66]
            #pragma unroll
            for (int j = 0; j < 64; ++j) {
                float pre = c1[j];
                pre = __fmaf_rn(ze0, sW1z[j], pre);
                pre = __fmaf_rn(ze1, sW1z[64 + j], pre);
                pre = __fmaf_rn(tcur, sW1t[j], pre);
                h1v[j] = fast_tanh(pre);
            }

            // layer 2 fwd + layer 3 + backward seed d = (eps @ W3^T) * tanh'(a2)
            float f0 = sb3[0], f1 = sb3[1];
            #pragma unroll
            for (int j = 0; j < 64; ++j) {
                const f32x2* wr = (const f32x2*)(sW2T + j * 64);
                f32x2 acc = {0.f, 0.f};
                #pragma unroll
                for (int i = 0; i < 32; ++i) {
                    f32x2 hp = { h1v[2 * i], h1v[2 * i + 1] };
                    acc += hp * wr[i];
                }
                float a = acc.x + acc.y + sb2[j];
                float hj = fast_tanh(a);
                float w30 = sW3[2 * j], w31 = sW3[2 * j + 1];
                f0 = __fmaf_rn(hj, w30, f0);
                f1 = __fmaf_rn(hj, w31, f1);
                dv[j] = (e0 * w30 + e1 * w31) * (1.f - hj * hj);
            }

            // backward: d_h1 = W2 @ d, then through tanh' and z-rows of W1
            float g0 = 0.f, g1 = 0.f;
            #pragma unroll
            for (int i = 0; i < 64; ++i) {
                const f32x2* wr = (const f32x2*)(sW2 + i * 64);
                f32x2 acc = {0.f, 0.f};
                #pragma unroll
                for (int jj = 0; jj < 32; ++jj) {
                    f32x2 dp = { dv[2 * jj], dv[2 * jj + 1] };
                    acc += wr[jj] * dp;
                }
                float sder = (acc.x + acc.y) * (1.f - h1v[i] * h1v[i]);
                g0 = __fmaf_rn(sW1z[i], sder, g0);
                g1 = __fmaf_rn(sW1z[64 + i], sder, g1);
            }
            float negdiv = -(g0 * e0 + g1 * e1);

            float w = (st == 1 || st == 2) ? 2.f : 1.f;
            zs0 = __fmaf_rn(w, f0, zs0);
            zs1 = __fmaf_rn(w, f1, zs1);
            ls  = __fmaf_rn(w, negdiv, ls);
            if (st < 3) {
                float cn = (st == 2) ? 1.f : 0.5f;
                ze0 = __fmaf_rn(cn * hstep, f0, z0);
                ze1 = __fmaf_rn(cn * hstep, f1, z1);
            }
        }
        const float h6 = hstep * (1.f / 6.f);
        z0 = __fmaf_rn(h6, zs0, z0);
        z1 = __fmaf_rn(h6, zs1, z1);
        lp = __fmaf_rn(h6, ls, lp);
    }

    out[2 * s]     = z0;
    out[2 * s + 1] = z1;
    out[2 * nb + s] = lp;
}

extern "C" void kernel_launch(void* const* d_in, const int* in_sizes, int n_in,
                              void* d_out, int out_size, void* d_ws, size_t ws_size,
                              hipStream_t stream) {
    const float* x   = (const float*)d_in[0];
    const float* ctx = (const float*)d_in[1];
    const float* eps = (const float*)d_in[2];
    const float* W1  = (const float*)d_in[3];
    const float* b1  = (const float*)d_in[4];
    const float* W2  = (const float*)d_in[5];
    const float* b2  = (const float*)d_in[6];
    const float* W3  = (const float*)d_in[7];
    const float* b3  = (const float*)d_in[8];
    float* out = (float*)d_out;

    int nb = in_sizes[0] / 2;  // x is [B,2]
    int grid = (nb + 255) / 256;
    hipLaunchKernelGGL(cnf_rk4_kernel, dim3(grid), dim3(256), 0, stream,
                       x, ctx, eps, W1, b1, W2, b2, W3, b3, out, nb);
}

// Round 3
// 2738.730 us; speedup vs baseline: 107.5060x; 107.5060x over previous
//
#include <hip/hip_runtime.h>
#include <cstddef>

typedef __attribute__((__ext_vector_type__(8))) short bf16x8;
typedef __attribute__((__ext_vector_type__(4))) float f32x4;

#define MFMA16(a, b, c) __builtin_amdgcn_mfma_f32_16x16x32_bf16((a), (b), (c), 0, 0, 0)

__device__ __forceinline__ unsigned short bf16_rne(float f) {
    unsigned int u = __float_as_uint(f);
    u += 0x7fffu + ((u >> 16) & 1u);
    return (unsigned short)(u >> 16);
}
__device__ __forceinline__ float bf16_to_f32(unsigned short h) {
    return __uint_as_float(((unsigned int)h) << 16);
}
__device__ __forceinline__ float tanh_fast(float x) {
    // tanh(x) = 1 - 2/(e^{2x}+1); saturates correctly at +-1 without clamping
    float e = __expf(2.f * x);
    return __builtin_fmaf(-2.f, __builtin_amdgcn_rcpf(e + 1.f), 1.f);
}

// One wave = 16 samples. MFMA 16x16x32 bf16 layouts (HW-verified, guide §3):
//   C/D: col = lane&15, row = (lane>>4)*4 + reg
//   A  : A[m = lane&15][k = (lane>>4)*8 + j], j=0..7 (short8 = 16B contiguous in k)
//   B  : B[k = (lane>>4)*8 + j][n = lane&15]
__global__ __launch_bounds__(256, 1)
void cnf_mfma_kernel(const float* __restrict__ x,
                     const float* __restrict__ ctx,
                     const float* __restrict__ eps,
                     const float* __restrict__ W1,
                     const float* __restrict__ b1,
                     const float* __restrict__ W2,
                     const float* __restrict__ b2,
                     const float* __restrict__ W3,
                     const float* __restrict__ b3,
                     float* __restrict__ out,
                     int nb)
{
    // per-wave transpose buffer: 16 rows x 64 bf16, row stride 72 ushorts (144B)
    // 144B = 36 dwords -> bank = (4*l15 + ...)%32 -> worst 2-way conflict (free)
    __shared__ __align__(16) unsigned short lds[4 * 16 * 72];

    const int tid  = threadIdx.x;
    const int lane = tid & 63;
    const int wv   = tid >> 6;
    const int l15  = lane & 15;
    const int quad = lane >> 4;
    unsigned short* tb = &lds[wv * 16 * 72];

    const int sBase = (blockIdx.x * 4 + wv) * 16;
    if (sBase >= nb) return;

    // ---- gather W2 fragments (init-only, L2-broadcast across blocks) ----
    // fwd: a2 = h1 @ W2        -> B[k=i][n=j] = W2[i][j]
    // bwd: dh1 = dv @ W2^T     -> B[k=j][n=i] = W2[i][j]
    bf16x8 w2f[2][4], w2b[2][4];
    #pragma unroll
    for (int ks = 0; ks < 2; ++ks) {
        #pragma unroll
        for (int t = 0; t < 4; ++t) {
            bf16x8 ff, fb;
            #pragma unroll
            for (int j = 0; j < 8; ++j) {
                ff[j] = (short)bf16_rne(W2[(ks * 32 + quad * 8 + j) * 64 + t * 16 + l15]);
                fb[j] = (short)bf16_rne(W2[(t * 16 + l15) * 64 + ks * 32 + quad * 8 + j]);
            }
            w2f[ks][t] = ff;
            w2b[ks][t] = fb;
        }
    }

    // ---- per-lane column scalars ----
    float w1z0[4], w1z1[4], w1tt[4], b2c[4], w30c[4], w31c[4];
    #pragma unroll
    for (int t = 0; t < 4; ++t) {
        int col = t * 16 + l15;
        w1z0[t] = W1[col];            // W1 row 0 (z0)
        w1z1[t] = W1[64 + col];       // W1 row 1 (z1)
        w1tt[t] = W1[66 * 64 + col];  // W1 row 66 (t feature)
        b2c[t]  = b2[col];
        w30c[t] = W3[2 * col];
        w31c[t] = W3[2 * col + 1];
    }
    const float b30 = b3[0], b31 = b3[1];

    // ---- c1 = b1 + ctx @ W1[2:66], via MFMA with hi/lo bf16 split ----
    f32x4 c1[4];
    {
        bf16x8 ah[2], al[2];
        #pragma unroll
        for (int ks = 0; ks < 2; ++ks) {
            bf16x8 h_, l_;
            #pragma unroll
            for (int j = 0; j < 8; ++j) {
                float v = ctx[(size_t)(sBase + l15) * 64 + ks * 32 + quad * 8 + j];
                unsigned short hh = bf16_rne(v);
                h_[j] = (short)hh;
                l_[j] = (short)bf16_rne(v - bf16_to_f32(hh));
            }
            ah[ks] = h_; al[ks] = l_;
        }
        #pragma unroll
        for (int t = 0; t < 4; ++t) {
            f32x4 acc;
            float b1c = b1[t * 16 + l15];
            acc[0] = b1c; acc[1] = b1c; acc[2] = b1c; acc[3] = b1c;
            #pragma unroll
            for (int ks = 0; ks < 2; ++ks) {
                bf16x8 bh, bl;
                #pragma unroll
                for (int j = 0; j < 8; ++j) {
                    float v = W1[(size_t)(2 + ks * 32 + quad * 8 + j) * 64 + t * 16 + l15];
                    unsigned short hh = bf16_rne(v);
                    bh[j] = (short)hh;
                    bl[j] = (short)bf16_rne(v - bf16_to_f32(hh));
                }
                acc = MFMA16(ah[ks], bh, acc);
                acc = MFMA16(al[ks], bh, acc);
                acc = MFMA16(ah[ks], bl, acc);
            }
            c1[t] = acc;
        }
    }

    // ---- z state (rows quad*4+r, replicated across the 16 lanes of a quad) ----
    float z0[4], z1[4], lp[4];
    #pragma unroll
    for (int r = 0; r < 4; ++r) {
        z0[r] = x[(size_t)(sBase + quad * 4 + r) * 2];
        z1[r] = x[(size_t)(sBase + quad * 4 + r) * 2 + 1];
        lp[r] = 0.f;
    }

    const float hstep = -1.f / 9.f;

    // eps prefetch (one stage ahead)
    float e0c[4], e1c[4], e0n[4], e1n[4];
    {
        const float* p = eps + (size_t)(sBase + quad * 4) * 2;
        #pragma unroll
        for (int r = 0; r < 4; ++r) { e0c[r] = p[2 * r]; e1c[r] = p[2 * r + 1]; }
    }

    #pragma unroll 1
    for (int k = 0; k < 9; ++k) {
        float ti = 1.f + (float)k * hstep;
        float ze0[4], ze1[4], zs0[4], zs1[4], lsum[4];
        #pragma unroll
        for (int r = 0; r < 4; ++r) {
            ze0[r] = z0[r]; ze1[r] = z1[r];
            zs0[r] = 0.f; zs1[r] = 0.f; lsum[r] = 0.f;
        }

        #pragma unroll 1
        for (int st = 0; st < 4; ++st) {
            float coef = (st == 0) ? 0.f : ((st == 3) ? 1.f : 0.5f);
            float tcur = ti + coef * hstep;
            int stg = k * 4 + st;
            if (stg < 35) {
                const float* p = eps + ((size_t)(stg + 1) * (size_t)nb + sBase + quad * 4) * 2;
                #pragma unroll
                for (int r = 0; r < 4; ++r) { e0n[r] = p[2 * r]; e1n[r] = p[2 * r + 1]; }
            }

            // ---- layer 1 (elementwise, C-layout) ----
            float h1[4][4];
            #pragma unroll
            for (int t = 0; t < 4; ++t) {
                #pragma unroll
                for (int r = 0; r < 4; ++r) {
                    float pre = c1[t][r];
                    pre = __builtin_fmaf(ze0[r], w1z0[t], pre);
                    pre = __builtin_fmaf(ze1[r], w1z1[t], pre);
                    pre = __builtin_fmaf(tcur,  w1tt[t], pre);
                    h1[t][r] = tanh_fast(pre);
                }
            }

            // ---- transpose h1 -> A-layout (wave-private LDS, no barrier) ----
            #pragma unroll
            for (int t = 0; t < 4; ++t)
                #pragma unroll
                for (int r = 0; r < 4; ++r)
                    tb[(quad * 4 + r) * 72 + t * 16 + l15] = bf16_rne(h1[t][r]);
            __asm__ volatile("s_waitcnt lgkmcnt(0)" ::: "memory");
            bf16x8 a1k0 = *(const bf16x8*)&tb[l15 * 72 + quad * 8];
            bf16x8 a1k1 = *(const bf16x8*)&tb[l15 * 72 + 32 + quad * 8];

            // ---- layer 2 fwd: 8 MFMAs, acc seeded with b2 ----
            f32x4 acc[4];
            #pragma unroll
            for (int t = 0; t < 4; ++t) {
                f32x4 a; a[0] = b2c[t]; a[1] = b2c[t]; a[2] = b2c[t]; a[3] = b2c[t];
                a = MFMA16(a1k0, w2f[0][t], a);
                a = MFMA16(a1k1, w2f[1][t], a);
                acc[t] = a;
            }

            // ---- h2 = tanh(a2); f partials; dv seed ----
            float f0p[4] = {0.f, 0.f, 0.f, 0.f}, f1p[4] = {0.f, 0.f, 0.f, 0.f};
            float dvv[4][4];
            #pragma unroll
            for (int t = 0; t < 4; ++t) {
                #pragma unroll
                for (int r = 0; r < 4; ++r) {
                    float h2 = tanh_fast(acc[t][r]);
                    f0p[r] = __builtin_fmaf(h2, w30c[t], f0p[r]);
                    f1p[r] = __builtin_fmaf(h2, w31c[t], f1p[r]);
                    float td = __builtin_fmaf(-h2, h2, 1.f);
                    dvv[t][r] = (e0c[r] * w30c[t] + e1c[r] * w31c[t]) * td;
                }
            }
            // butterfly over the 16 cols
            #pragma unroll
            for (int m = 1; m < 16; m <<= 1) {
                #pragma unroll
                for (int r = 0; r < 4; ++r) {
                    f0p[r] += __shfl_xor(f0p[r], m, 16);
                    f1p[r] += __shfl_xor(f1p[r], m, 16);
                }
            }
            float f0[4], f1[4];
            #pragma unroll
            for (int r = 0; r < 4; ++r) { f0[r] = f0p[r] + b30; f1[r] = f1p[r] + b31; }

            // ---- transpose dv -> A-layout ----
            __asm__ volatile("s_waitcnt lgkmcnt(0)" ::: "memory");
            #pragma unroll
            for (int t = 0; t < 4; ++t)
                #pragma unroll
                for (int r = 0; r < 4; ++r)
                    tb[(quad * 4 + r) * 72 + t * 16 + l15] = bf16_rne(dvv[t][r]);
            __asm__ volatile("s_waitcnt lgkmcnt(0)" ::: "memory");
            bf16x8 adk0 = *(const bf16x8*)&tb[l15 * 72 + quad * 8];
            bf16x8 adk1 = *(const bf16x8*)&tb[l15 * 72 + 32 + quad * 8];

            // ---- bwd: dh1 = dv @ W2^T, 8 MFMAs ----
            f32x4 acc2[4];
            #pragma unroll
            for (int t = 0; t < 4; ++t) {
                f32x4 a; a[0] = 0.f; a[1] = 0.f; a[2] = 0.f; a[3] = 0.f;
                a = MFMA16(adk0, w2b[0][t], a);
                a = MFMA16(adk1, w2b[1][t], a);
                acc2[t] = a;
            }

            // ---- sder = dh1 * tanh'(a1); g = sder @ W1z; butterfly ----
            float g0p[4] = {0.f, 0.f, 0.f, 0.f}, g1p[4] = {0.f, 0.f, 0.f, 0.f};
            #pragma unroll
            for (int t = 0; t < 4; ++t) {
                #pragma unroll
                for (int r = 0; r < 4; ++r) {
                    float hv = h1[t][r];
                    float sd = acc2[t][r] * __builtin_fmaf(-hv, hv, 1.f);
                    g0p[r] = __builtin_fmaf(sd, w1z0[t], g0p[r]);
                    g1p[r] = __builtin_fmaf(sd, w1z1[t], g1p[r]);
                }
            }
            #pragma unroll
            for (int m = 1; m < 16; m <<= 1) {
                #pragma unroll
                for (int r = 0; r < 4; ++r) {
                    g0p[r] += __shfl_xor(g0p[r], m, 16);
                    g1p[r] += __shfl_xor(g1p[r], m, 16);
                }
            }

            // ---- RK4 combine ----
            float wgt = (st == 1 || st == 2) ? 2.f : 1.f;
            #pragma unroll
            for (int r = 0; r < 4; ++r) {
                float nd = -(g0p[r] * e0c[r] + g1p[r] * e1c[r]);
                zs0[r] = __builtin_fmaf(wgt, f0[r], zs0[r]);
                zs1[r] = __builtin_fmaf(wgt, f1[r], zs1[r]);
                lsum[r] = __builtin_fmaf(wgt, nd, lsum[r]);
            }
            if (st < 3) {
                float cn = (st == 2) ? 1.f : 0.5f;
                #pragma unroll
                for (int r = 0; r < 4; ++r) {
                    ze0[r] = __builtin_fmaf(cn * hstep, f0[r], z0[r]);
                    ze1[r] = __builtin_fmaf(cn * hstep, f1[r], z1[r]);
                }
            }
            #pragma unroll
            for (int r = 0; r < 4; ++r) { e0c[r] = e0n[r]; e1c[r] = e1n[r]; }
        }

        const float h6 = hstep * (1.f / 6.f);
        #pragma unroll
        for (int r = 0; r < 4; ++r) {
            z0[r] = __builtin_fmaf(h6, zs0[r], z0[r]);
            z1[r] = __builtin_fmaf(h6, zs1[r], z1[r]);
            lp[r] = __builtin_fmaf(h6, lsum[r], lp[r]);
        }
    }

    if (l15 == 0) {
        #pragma unroll
        for (int r = 0; r < 4; ++r) {
            int s = sBase + quad * 4 + r;
            out[2 * s]     = z0[r];
            out[2 * s + 1] = z1[r];
            out[2 * nb + s] = lp[r];
        }
    }
}

extern "C" void kernel_launch(void* const* d_in, const int* in_sizes, int n_in,
                              void* d_out, int out_size, void* d_ws, size_t ws_size,
                              hipStream_t stream) {
    const float* x   = (const float*)d_in[0];
    const float* ctx = (const float*)d_in[1];
    const float* eps = (const float*)d_in[2];
    const float* W1  = (const float*)d_in[3];
    const float* b1  = (const float*)d_in[4];
    const float* W2  = (const float*)d_in[5];
    const float* b2  = (const float*)d_in[6];
    const float* W3  = (const float*)d_in[7];
    const float* b3  = (const float*)d_in[8];
    float* out = (float*)d_out;

    int nb = in_sizes[0] / 2;  // x is [B,2]
    int grid = (nb + 63) / 64; // 64 samples per 256-thread block (16 per wave)
    hipLaunchKernelGGL(cnf_mfma_kernel, dim3(grid), dim3(256), 0, stream,
                       x, ctx, eps, W1, b1, W2, b2, W3, b3, out, nb);
}

// Round 4
// 1898.904 us; speedup vs baseline: 155.0525x; 1.4423x over previous
//
#include <hip/hip_runtime.h>
#include <cstddef>

typedef __attribute__((__ext_vector_type__(8))) short bf16x8;
typedef __attribute__((__ext_vector_type__(4))) float f32x4;

#define MFMA16(a, b, c) __builtin_amdgcn_mfma_f32_16x16x32_bf16((a), (b), (c), 0, 0, 0)

__device__ __forceinline__ unsigned short bf16_rne(float f) {
    unsigned int u = __float_as_uint(f);
    u += 0x7fffu + ((u >> 16) & 1u);
    return (unsigned short)(u >> 16);
}
__device__ __forceinline__ float bf16_to_f32(unsigned short h) {
    return __uint_as_float(((unsigned int)h) << 16);
}
__device__ __forceinline__ float tanh_fast(float x) {
    // tanh(x) = 1 - 2/(e^{2x}+1); saturates correctly at +-1 without clamping
    float e = __expf(2.f * x);
    return __builtin_fmaf(-2.f, __builtin_amdgcn_rcpf(e + 1.f), 1.f);
}

// One wave = 16 samples. MFMA 16x16x32 bf16 layouts (HW-verified, guide §3):
//   C/D: col = lane&15, row = (lane>>4)*4 + reg
//   A  : A[m = lane&15][k = (lane>>4)*8 + j], j=0..7 (short8 = 16B contiguous in k)
//   B  : B[k = (lane>>4)*8 + j][n = lane&15]
//
// R4: W2 fragments live in LDS (were 64 VGPRs/lane in R3 -> 1 wave/SIMD,
// VALUBusy 49%). launch_bounds(256,2) forces combined regs <=256 -> 2 waves/SIMD.
__global__ __launch_bounds__(256, 2)
void cnf_mfma_kernel(const float* __restrict__ x,
                     const float* __restrict__ ctx,
                     const float* __restrict__ eps,
                     const float* __restrict__ W1,
                     const float* __restrict__ b1,
                     const float* __restrict__ W2,
                     const float* __restrict__ b2,
                     const float* __restrict__ W3,
                     const float* __restrict__ b3,
                     float* __restrict__ out,
                     int nb)
{
    // W2 B-fragments, pre-packed per-lane: [ks][t][lane][j] (16B/lane contiguous)
    __shared__ __align__(16) unsigned short sW2f[4096];  // fwd: B[k=i][n=c]=W2[i][c]
    __shared__ __align__(16) unsigned short sW2b[4096];  // bwd: B[k=c][n=i]=W2[i][c]
    // per-wave transpose buffer: 16 rows x 64 bf16, row stride 72 ushorts (144B,
    // 16B-aligned rows for ds_read_b128; worst 4-way conflict on b16 writes = minor)
    __shared__ __align__(16) unsigned short lds[4 * 16 * 72];

    const int tid  = threadIdx.x;
    const int lane = tid & 63;
    const int wv   = tid >> 6;
    const int l15  = lane & 15;
    const int quad = lane >> 4;
    unsigned short* tb = &lds[wv * 16 * 72];

    // ---- cooperative W2 fragment fill (both layouts), once per block ----
    for (int idx = tid; idx < 4096; idx += 256) {
        int i = idx >> 6, c = idx & 63;
        unsigned short v = bf16_rne(W2[idx]);
        // fwd frag: ks=i>>5, j=i&7, quad=(i>>3)&3, t=c>>4, l15=c&15
        sW2f[(((i >> 5) * 4 + (c >> 4)) * 64 + ((i >> 3) & 3) * 16 + (c & 15)) * 8 + (i & 7)] = v;
        // bwd frag: ks=c>>5, j=c&7, quad=(c>>3)&3, t=i>>4, l15=i&15
        sW2b[(((c >> 5) * 4 + (i >> 4)) * 64 + ((c >> 3) & 3) * 16 + (i & 15)) * 8 + (c & 7)] = v;
    }
    __syncthreads();

    const int sBase = (blockIdx.x * 4 + wv) * 16;
    if (sBase >= nb) return;

    // ---- per-lane column scalars ----
    float w1z0[4], w1z1[4], w1tt[4], b2c[4], w30c[4], w31c[4];
    #pragma unroll
    for (int t = 0; t < 4; ++t) {
        int col = t * 16 + l15;
        w1z0[t] = W1[col];            // W1 row 0 (z0)
        w1z1[t] = W1[64 + col];       // W1 row 1 (z1)
        w1tt[t] = W1[66 * 64 + col];  // W1 row 66 (t feature)
        b2c[t]  = b2[col];
        w30c[t] = W3[2 * col];
        w31c[t] = W3[2 * col + 1];
    }
    const float b30 = b3[0], b31 = b3[1];

    // ---- c1 = b1 + ctx @ W1[2:66], via MFMA with hi/lo bf16 split ----
    f32x4 c1[4];
    {
        bf16x8 ah[2], al[2];
        #pragma unroll
        for (int ks = 0; ks < 2; ++ks) {
            bf16x8 h_, l_;
            #pragma unroll
            for (int j = 0; j < 8; ++j) {
                float v = ctx[(size_t)(sBase + l15) * 64 + ks * 32 + quad * 8 + j];
                unsigned short hh = bf16_rne(v);
                h_[j] = (short)hh;
                l_[j] = (short)bf16_rne(v - bf16_to_f32(hh));
            }
            ah[ks] = h_; al[ks] = l_;
        }
        #pragma unroll
        for (int t = 0; t < 4; ++t) {
            f32x4 acc;
            float b1c = b1[t * 16 + l15];
            acc[0] = b1c; acc[1] = b1c; acc[2] = b1c; acc[3] = b1c;
            #pragma unroll
            for (int ks = 0; ks < 2; ++ks) {
                bf16x8 bh, bl;
                #pragma unroll
                for (int j = 0; j < 8; ++j) {
                    float v = W1[(size_t)(2 + ks * 32 + quad * 8 + j) * 64 + t * 16 + l15];
                    unsigned short hh = bf16_rne(v);
                    bh[j] = (short)hh;
                    bl[j] = (short)bf16_rne(v - bf16_to_f32(hh));
                }
                acc = MFMA16(ah[ks], bh, acc);
                acc = MFMA16(al[ks], bh, acc);
                acc = MFMA16(ah[ks], bl, acc);
            }
            c1[t] = acc;
        }
    }

    // ---- z state (rows quad*4+r, replicated across the 16 lanes of a quad) ----
    float z0[4], z1[4], lp[4];
    #pragma unroll
    for (int r = 0; r < 4; ++r) {
        z0[r] = x[(size_t)(sBase + quad * 4 + r) * 2];
        z1[r] = x[(size_t)(sBase + quad * 4 + r) * 2 + 1];
        lp[r] = 0.f;
    }

    const float hstep = -1.f / 9.f;

    // eps prefetch (one stage ahead)
    float e0c[4], e1c[4], e0n[4], e1n[4];
    {
        const float* p = eps + (size_t)(sBase + quad * 4) * 2;
        #pragma unroll
        for (int r = 0; r < 4; ++r) { e0c[r] = p[2 * r]; e1c[r] = p[2 * r + 1]; }
    }

    #pragma unroll 1
    for (int k = 0; k < 9; ++k) {
        float ti = 1.f + (float)k * hstep;
        float ze0[4], ze1[4], zs0[4], zs1[4], lsum[4];
        #pragma unroll
        for (int r = 0; r < 4; ++r) {
            ze0[r] = z0[r]; ze1[r] = z1[r];
            zs0[r] = 0.f; zs1[r] = 0.f; lsum[r] = 0.f;
        }

        #pragma unroll 1
        for (int st = 0; st < 4; ++st) {
            // opaque zero: blocks LICM from hoisting the 16 W2-fragment
            // ds_read_b128s out of the loop (that would re-pin 128 VGPRs)
            int zo = 0;
            __asm__ volatile("" : "+v"(zo));
            const unsigned short* pf = sW2f + zo;
            const unsigned short* pb = sW2b + zo;

            float coef = (st == 0) ? 0.f : ((st == 3) ? 1.f : 0.5f);
            float tcur = ti + coef * hstep;
            int stg = k * 4 + st;
            if (stg < 35) {
                const float* p = eps + ((size_t)(stg + 1) * (size_t)nb + sBase + quad * 4) * 2;
                #pragma unroll
                for (int r = 0; r < 4; ++r) { e0n[r] = p[2 * r]; e1n[r] = p[2 * r + 1]; }
            }

            // ---- layer 1 (elementwise, C-layout) ----
            float h1[4][4];
            #pragma unroll
            for (int t = 0; t < 4; ++t) {
                #pragma unroll
                for (int r = 0; r < 4; ++r) {
                    float pre = c1[t][r];
                    pre = __builtin_fmaf(ze0[r], w1z0[t], pre);
                    pre = __builtin_fmaf(ze1[r], w1z1[t], pre);
                    pre = __builtin_fmaf(tcur,  w1tt[t], pre);
                    h1[t][r] = tanh_fast(pre);
                }
            }

            // ---- transpose h1 -> A-layout (wave-private LDS, no barrier) ----
            #pragma unroll
            for (int t = 0; t < 4; ++t)
                #pragma unroll
                for (int r = 0; r < 4; ++r)
                    tb[(quad * 4 + r) * 72 + t * 16 + l15] = bf16_rne(h1[t][r]);
            __asm__ volatile("s_waitcnt lgkmcnt(0)" ::: "memory");
            bf16x8 a1k0 = *(const bf16x8*)&tb[l15 * 72 + quad * 8];
            bf16x8 a1k1 = *(const bf16x8*)&tb[l15 * 72 + 32 + quad * 8];

            // ---- layer 2 fwd: 8 MFMAs, B-fragments streamed from LDS ----
            f32x4 acc[4];
            #pragma unroll
            for (int t = 0; t < 4; ++t) {
                bf16x8 bk0 = *(const bf16x8*)&pf[(t * 64 + lane) * 8];
                bf16x8 bk1 = *(const bf16x8*)&pf[((4 + t) * 64 + lane) * 8];
                f32x4 a; a[0] = b2c[t]; a[1] = b2c[t]; a[2] = b2c[t]; a[3] = b2c[t];
                a = MFMA16(a1k0, bk0, a);
                a = MFMA16(a1k1, bk1, a);
                acc[t] = a;
            }

            // ---- h2 = tanh(a2); f partials; dv seed ----
            float f0p[4] = {0.f, 0.f, 0.f, 0.f}, f1p[4] = {0.f, 0.f, 0.f, 0.f};
            float dvv[4][4];
            #pragma unroll
            for (int t = 0; t < 4; ++t) {
                #pragma unroll
                for (int r = 0; r < 4; ++r) {
                    float h2 = tanh_fast(acc[t][r]);
                    f0p[r] = __builtin_fmaf(h2, w30c[t], f0p[r]);
                    f1p[r] = __builtin_fmaf(h2, w31c[t], f1p[r]);
                    float td = __builtin_fmaf(-h2, h2, 1.f);
                    dvv[t][r] = (e0c[r] * w30c[t] + e1c[r] * w31c[t]) * td;
                }
            }
            // butterfly over the 16 cols
            #pragma unroll
            for (int m = 1; m < 16; m <<= 1) {
                #pragma unroll
                for (int r = 0; r < 4; ++r) {
                    f0p[r] += __shfl_xor(f0p[r], m, 16);
                    f1p[r] += __shfl_xor(f1p[r], m, 16);
                }
            }
            float f0[4], f1[4];
            #pragma unroll
            for (int r = 0; r < 4; ++r) { f0[r] = f0p[r] + b30; f1[r] = f1p[r] + b31; }

            // ---- transpose dv -> A-layout ----
            __asm__ volatile("s_waitcnt lgkmcnt(0)" ::: "memory");
            #pragma unroll
            for (int t = 0; t < 4; ++t)
                #pragma unroll
                for (int r = 0; r < 4; ++r)
                    tb[(quad * 4 + r) * 72 + t * 16 + l15] = bf16_rne(dvv[t][r]);
            __asm__ volatile("s_waitcnt lgkmcnt(0)" ::: "memory");
            bf16x8 adk0 = *(const bf16x8*)&tb[l15 * 72 + quad * 8];
            bf16x8 adk1 = *(const bf16x8*)&tb[l15 * 72 + 32 + quad * 8];

            // ---- bwd: dh1 = dv @ W2^T, 8 MFMAs, B-fragments from LDS ----
            f32x4 acc2[4];
            #pragma unroll
            for (int t = 0; t < 4; ++t) {
                bf16x8 bk0 = *(const bf16x8*)&pb[(t * 64 + lane) * 8];
                bf16x8 bk1 = *(const bf16x8*)&pb[((4 + t) * 64 + lane) * 8];
                f32x4 a; a[0] = 0.f; a[1] = 0.f; a[2] = 0.f; a[3] = 0.f;
                a = MFMA16(adk0, bk0, a);
                a = MFMA16(adk1, bk1, a);
                acc2[t] = a;
            }

            // ---- sder = dh1 * tanh'(a1); g = sder @ W1z; butterfly ----
            float g0p[4] = {0.f, 0.f, 0.f, 0.f}, g1p[4] = {0.f, 0.f, 0.f, 0.f};
            #pragma unroll
            for (int t = 0; t < 4; ++t) {
                #pragma unroll
                for (int r = 0; r < 4; ++r) {
                    float hv = h1[t][r];
                    float sd = acc2[t][r] * __builtin_fmaf(-hv, hv, 1.f);
                    g0p[r] = __builtin_fmaf(sd, w1z0[t], g0p[r]);
                    g1p[r] = __builtin_fmaf(sd, w1z1[t], g1p[r]);
                }
            }
            #pragma unroll
            for (int m = 1; m < 16; m <<= 1) {
                #pragma unroll
                for (int r = 0; r < 4; ++r) {
                    g0p[r] += __shfl_xor(g0p[r], m, 16);
                    g1p[r] += __shfl_xor(g1p[r], m, 16);
                }
            }

            // ---- RK4 combine ----
            float wgt = (st == 1 || st == 2) ? 2.f : 1.f;
            #pragma unroll
            for (int r = 0; r < 4; ++r) {
                float nd = -(g0p[r] * e0c[r] + g1p[r] * e1c[r]);
                zs0[r] = __builtin_fmaf(wgt, f0[r], zs0[r]);
                zs1[r] = __builtin_fmaf(wgt, f1[r], zs1[r]);
                lsum[r] = __builtin_fmaf(wgt, nd, lsum[r]);
            }
            if (st < 3) {
                float cn = (st == 2) ? 1.f : 0.5f;
                #pragma unroll
                for (int r = 0; r < 4; ++r) {
                    ze0[r] = __builtin_fmaf(cn * hstep, f0[r], z0[r]);
                    ze1[r] = __builtin_fmaf(cn * hstep, f1[r], z1[r]);
                }
            }
            #pragma unroll
            for (int r = 0; r < 4; ++r) { e0c[r] = e0n[r]; e1c[r] = e1n[r]; }
        }

        const float h6 = hstep * (1.f / 6.f);
        #pragma unroll
        for (int r = 0; r < 4; ++r) {
            z0[r] = __builtin_fmaf(h6, zs0[r], z0[r]);
            z1[r] = __builtin_fmaf(h6, zs1[r], z1[r]);
            lp[r] = __builtin_fmaf(h6, lsum[r], lp[r]);
        }
    }

    if (l15 == 0) {
        #pragma unroll
        for (int r = 0; r < 4; ++r) {
            int s = sBase + quad * 4 + r;
            out[2 * s]     = z0[r];
            out[2 * s + 1] = z1[r];
            out[2 * nb + s] = lp[r];
        }
    }
}

extern "C" void kernel_launch(void* const* d_in, const int* in_sizes, int n_in,
                              void* d_out, int out_size, void* d_ws, size_t ws_size,
                              hipStream_t stream) {
    const float* x   = (const float*)d_in[0];
    const float* ctx = (const float*)d_in[1];
    const float* eps = (const float*)d_in[2];
    const float* W1  = (const float*)d_in[3];
    const float* b1  = (const float*)d_in[4];
    const float* W2  = (const float*)d_in[5];
    const float* b2  = (const float*)d_in[6];
    const float* W3  = (const float*)d_in[7];
    const float* b3  = (const float*)d_in[8];
    float* out = (float*)d_out;

    int nb = in_sizes[0] / 2;  // x is [B,2]
    int grid = (nb + 63) / 64; // 64 samples per 256-thread block (16 per wave)
    hipLaunchKernelGGL(cnf_mfma_kernel, dim3(grid), dim3(256), 0, stream,
                       x, ctx, eps, W1, b1, W2, b2, W3, b3, out, nb);
}